// Round 5
// baseline (194.166 us; speedup 1.0000x reference)
//
#include <hip/hip_runtime.h>
#include <cstdint>
#include <cstddef>
#include <math.h>

// Problem constants (from reference)
#define NNODES 20000
#define NEDGES 320000
#define TDIM   8
#define CDIM   32
#define RROWS  (NNODES * TDIM)           // 160000 rows of 32 floats
#define NELEM  (RROWS * CDIM)            // 5,120,000 elements per [N,T,C] tensor
#define ROWBLK (TDIM * CDIM)             // 256 floats per node (all tau, all ch)

static __device__ __forceinline__ float4 fmax4(float4 a, float4 b) {
    return make_float4(fmaxf(a.x, b.x), fmaxf(a.y, b.y),
                       fmaxf(a.z, b.z), fmaxf(a.w, b.w));
}

// ---------------------------------------------------------------------------
// Fused linear kernel: h = in @ W ; hu = h @ U.  One row (32 floats) per thread.
// Weights staged in LDS.  `in`/`hu` may alias (per-thread row RAW), so no
// __restrict__ on them.
// ---------------------------------------------------------------------------
__global__ __launch_bounds__(256) void linear2_kernel(
    const float* in,                // [RROWS, 32]
    const float* __restrict__ W,    // [32, 32]
    const float* __restrict__ U,    // [32, 32]
    float* __restrict__ h,          // [RROWS, 32]
    float* hu)                      // [RROWS, 32]
{
    __shared__ float sW[CDIM][CDIM];
    __shared__ float sU[CDIM][CDIM];
    int tid = threadIdx.x;
#pragma unroll
    for (int i = 0; i < 4; ++i) {
        int idx = tid + i * 256;
        ((float*)sW)[idx] = W[idx];
        ((float*)sU)[idx] = U[idx];
    }
    __syncthreads();

    int row = blockIdx.x * 256 + tid;
    if (row >= RROWS) return;

    const float* xr = in + (size_t)row * CDIM;
    float x[CDIM];
#pragma unroll
    for (int k = 0; k < CDIM / 4; ++k) {
        float4 v = ((const float4*)xr)[k];
        x[4 * k + 0] = v.x; x[4 * k + 1] = v.y;
        x[4 * k + 2] = v.z; x[4 * k + 3] = v.w;
    }

    float hr[CDIM];
#pragma unroll
    for (int c = 0; c < CDIM; ++c) {
        float acc = 0.f;
#pragma unroll
        for (int k = 0; k < CDIM; ++k) acc += x[k] * sW[k][c];
        hr[c] = acc;
    }

    float* hrow = h + (size_t)row * CDIM;
#pragma unroll
    for (int k = 0; k < CDIM / 4; ++k) {
        ((float4*)hrow)[k] = make_float4(hr[4 * k], hr[4 * k + 1],
                                         hr[4 * k + 2], hr[4 * k + 3]);
    }

#pragma unroll
    for (int c = 0; c < CDIM; ++c) {
        float acc = 0.f;
#pragma unroll
        for (int k = 0; k < CDIM; ++k) acc += hr[k] * sU[k][c];
        x[c] = acc;
    }

    float* hurow = hu + (size_t)row * CDIM;
#pragma unroll
    for (int k = 0; k < CDIM / 4; ++k) {
        ((float4*)hurow)[k] = make_float4(x[4 * k], x[4 * k + 1],
                                          x[4 * k + 2], x[4 * k + 3]);
    }
}

// ---------------------------------------------------------------------------
// CSR build: hist -> 3-stage parallel scan -> scatter.  Once per launch.
// ---------------------------------------------------------------------------
__global__ __launch_bounds__(256) void zero_counts_kernel(int* __restrict__ counts)
{
    int i = blockIdx.x * 256 + threadIdx.x;
    if (i < NNODES) counts[i] = 0;
}

__global__ __launch_bounds__(256) void hist_kernel(
    const int* __restrict__ ei, int* __restrict__ counts)
{
    int e = blockIdx.x * 256 + threadIdx.x;
    if (e < NEDGES) atomicAdd(&counts[ei[NEDGES + e]], 1);
}

// per-block sums of counts (79 blocks x 256)
__global__ __launch_bounds__(256) void blocksum_kernel(
    const int* __restrict__ counts, int* __restrict__ bsum)
{
    __shared__ int sd[256];
    int tid = threadIdx.x;
    int i = blockIdx.x * 256 + tid;
    sd[tid] = (i < NNODES) ? counts[i] : 0;
    __syncthreads();
#pragma unroll
    for (int off = 128; off > 0; off >>= 1) {
        if (tid < off) sd[tid] += sd[tid + off];
        __syncthreads();
    }
    if (tid == 0) bsum[blockIdx.x] = sd[0];
}

// exclusive scan of the 79 block sums (1 block, 128 threads)
__global__ __launch_bounds__(128) void bscan_kernel(
    const int* __restrict__ bsum, int* __restrict__ bbase, int nblocks)
{
    __shared__ int sd[128];
    int tid = threadIdx.x;
    int v = (tid < nblocks) ? bsum[tid] : 0;
    sd[tid] = v;
    __syncthreads();
#pragma unroll
    for (int off = 1; off < 128; off <<= 1) {
        int t = (tid >= off) ? sd[tid - off] : 0;
        __syncthreads();
        sd[tid] += t;
        __syncthreads();
    }
    if (tid < nblocks) bbase[tid] = sd[tid] - v;   // exclusive
}

// local exclusive scan + add block base -> offsets, cursor
__global__ __launch_bounds__(256) void localscan_kernel(
    const int* __restrict__ counts, const int* __restrict__ bbase,
    int* __restrict__ offsets, int* __restrict__ cursor)
{
    __shared__ int sd[256];
    int tid = threadIdx.x;
    int i = blockIdx.x * 256 + tid;
    int v = (i < NNODES) ? counts[i] : 0;
    sd[tid] = v;
    __syncthreads();
#pragma unroll
    for (int off = 1; off < 256; off <<= 1) {
        int t = (tid >= off) ? sd[tid - off] : 0;
        __syncthreads();
        sd[tid] += t;
        __syncthreads();
    }
    int excl = bbase[blockIdx.x] + sd[tid] - v;
    if (i < NNODES) { offsets[i] = excl; cursor[i] = excl; }
    if (i == NNODES - 1) offsets[NNODES] = NEDGES;
}

__global__ __launch_bounds__(256) void scatter_kernel(
    const int* __restrict__ ei,
    int* __restrict__ cursor,
    int* __restrict__ csr_src)
{
    int e = blockIdx.x * 256 + threadIdx.x;
    if (e < NEDGES) {
        int t = ei[NEDGES + e];
        int pos = atomicAdd(&cursor[t], 1);
        csr_src[pos] = ei[e];
    }
}

// ---------------------------------------------------------------------------
// Aggregation kernel: ONE WAVE PER NODE (block = 4 nodes x 1 wave).
// Wave lane = tau*8 + li; lane owns 4 channels (float4).  Per (edge,tau):
// dot = 4 FMA + 3-step shfl within the 8-lane tau group.  Edge loop unrolled
// by 4 -> 4 independent coalesced 1KB row gathers in flight.  All addressing
// in 32-bit byte offsets (hu spans 20.5MB < 2^31) -> saddr-form loads.
// No LDS, no __syncthreads, no cross-wave combine.
// Writes out = leaky_relu(h + agg, 0.01) once.  `h`/`out` may alias.
// ---------------------------------------------------------------------------
__global__ __launch_bounds__(256) void agg_kernel(
    const int* __restrict__ offsets,
    const int* __restrict__ csr_src,
    const float* __restrict__ hu,   // gather source [RROWS,32]
    const float* h,                 // [RROWS,32]
    float* out)                     // [RROWS,32]
{
    int tid = threadIdx.x;
    int n = blockIdx.x * 4 + (tid >> 6);     // node for this wave
    int l64 = tid & 63;                      // tau*8 + li
    uint32_t rowOff  = (uint32_t)l64 * 16u;  // byte offset inside 1KB node block
    uint32_t nodeOff = (uint32_t)n * 1024u + rowOff;

    const char* hub = (const char*)hu;
    float4 bv = *(const float4*)(hub + nodeOff);   // x_i quad for this (tau,ch4)

    int k0 = offsets[n];
    int k1 = offsets[n + 1];

    float4 m = make_float4(-INFINITY, -INFINITY, -INFINITY, -INFINITY);

    int k = k0;
    for (; k + 4 <= k1; k += 4) {
        int s0 = csr_src[k + 0];
        int s1 = csr_src[k + 1];
        int s2 = csr_src[k + 2];
        int s3 = csr_src[k + 3];
        float4 a0 = *(const float4*)(hub + (((uint32_t)s0 << 10) + rowOff));
        float4 a1 = *(const float4*)(hub + (((uint32_t)s1 << 10) + rowOff));
        float4 a2 = *(const float4*)(hub + (((uint32_t)s2 << 10) + rowOff));
        float4 a3 = *(const float4*)(hub + (((uint32_t)s3 << 10) + rowOff));
        float p0 = a0.x * bv.x + a0.y * bv.y + a0.z * bv.z + a0.w * bv.w;
        float p1 = a1.x * bv.x + a1.y * bv.y + a1.z * bv.z + a1.w * bv.w;
        float p2 = a2.x * bv.x + a2.y * bv.y + a2.z * bv.z + a2.w * bv.w;
        float p3 = a3.x * bv.x + a3.y * bv.y + a3.z * bv.z + a3.w * bv.w;
        p0 += __shfl_xor(p0, 1); p1 += __shfl_xor(p1, 1);
        p2 += __shfl_xor(p2, 1); p3 += __shfl_xor(p3, 1);
        p0 += __shfl_xor(p0, 2); p1 += __shfl_xor(p1, 2);
        p2 += __shfl_xor(p2, 2); p3 += __shfl_xor(p3, 2);
        p0 += __shfl_xor(p0, 4); p1 += __shfl_xor(p1, 4);
        p2 += __shfl_xor(p2, 4); p3 += __shfl_xor(p3, 4);
        float g0 = 1.f / (1.f + __expf(-p0));
        float g1 = 1.f / (1.f + __expf(-p1));
        float g2 = 1.f / (1.f + __expf(-p2));
        float g3 = 1.f / (1.f + __expf(-p3));
        m = fmax4(m, make_float4(a0.x * g0, a0.y * g0, a0.z * g0, a0.w * g0));
        m = fmax4(m, make_float4(a1.x * g1, a1.y * g1, a1.z * g1, a1.w * g1));
        m = fmax4(m, make_float4(a2.x * g2, a2.y * g2, a2.z * g2, a2.w * g2));
        m = fmax4(m, make_float4(a3.x * g3, a3.y * g3, a3.z * g3, a3.w * g3));
    }
    for (; k < k1; ++k) {
        int s0 = csr_src[k];
        float4 a0 = *(const float4*)(hub + (((uint32_t)s0 << 10) + rowOff));
        float p0 = a0.x * bv.x + a0.y * bv.y + a0.z * bv.z + a0.w * bv.w;
        p0 += __shfl_xor(p0, 1);
        p0 += __shfl_xor(p0, 2);
        p0 += __shfl_xor(p0, 4);
        float g0 = 1.f / (1.f + __expf(-p0));
        m = fmax4(m, make_float4(a0.x * g0, a0.y * g0, a0.z * g0, a0.w * g0));
    }

    bool has = (k1 > k0);
    float4 hv = *(const float4*)((const char*)h + nodeOff);
    float ax = has ? m.x : 0.f;
    float ay = has ? m.y : 0.f;
    float az = has ? m.z : 0.f;
    float aw = has ? m.w : 0.f;
    float vx = hv.x + ax, vy = hv.y + ay, vz = hv.z + az, vw = hv.w + aw;
    float4 o;
    o.x = (vx >= 0.f) ? vx : 0.01f * vx;
    o.y = (vy >= 0.f) ? vy : 0.01f * vy;
    o.z = (vz >= 0.f) ? vz : 0.01f * vz;
    o.w = (vw >= 0.f) ? vw : 0.01f * vw;
    *(float4*)((char*)out + nodeOff) = o;
}

// ---------------------------------------------------------------------------
// Orchestration.
// ws: [counts N][offsets N+1][cursor N][bsum 128][bbase 128][csr E][pad][A NELEM]
// Layer 1: linear2(X)->h1=A, hu1=d_out;  agg(hu=d_out,h=A)->c1=A (in place)
// Layer 2: linear2(A)->h2=d_out, hu2=A (in place); agg(hu=A,h=d_out)->d_out
// ---------------------------------------------------------------------------
extern "C" void kernel_launch(void* const* d_in, const int* in_sizes, int n_in,
                              void* d_out, int out_size, void* d_ws, size_t ws_size,
                              hipStream_t stream)
{
    const float* X   = (const float*)d_in[0];
    const int*   ei  = (const int*)  d_in[1];
    // d_in[2]=edge_attr, d_in[4]=We1, d_in[7]=We2: dead code in reference
    const float* Wn1 = (const float*)d_in[3];
    const float* u1  = (const float*)d_in[5];
    const float* Wn2 = (const float*)d_in[6];
    const float* u2  = (const float*)d_in[8];

    float* out = (float*)d_out;

    int* counts  = (int*)d_ws;
    int* offsets = counts + NNODES;          // NNODES+1
    int* cursor  = offsets + NNODES + 1;
    int* bsum    = cursor + NNODES;          // 128
    int* bbase   = bsum + 128;               // 128
    int* csr     = bbase + 128;              // NEDGES
    float* A = (float*)(((uintptr_t)(csr + NEDGES) + 255) & ~(uintptr_t)255);

    const int rowBlocks  = (RROWS + 255) / 256;    // 625
    const int edgeBlocks = (NEDGES + 255) / 256;   // 1250
    const int nodeBlocks = (NNODES + 255) / 256;   // 79
    const int aggBlocks  = NNODES / 4;             // 5000 (4 waves = 4 nodes/block)

    // ---- CSR build (shared by both layers) ----
    zero_counts_kernel<<<nodeBlocks, 256, 0, stream>>>(counts);
    hist_kernel<<<edgeBlocks, 256, 0, stream>>>(ei, counts);
    blocksum_kernel<<<nodeBlocks, 256, 0, stream>>>(counts, bsum);
    bscan_kernel<<<1, 128, 0, stream>>>(bsum, bbase, nodeBlocks);
    localscan_kernel<<<nodeBlocks, 256, 0, stream>>>(counts, bbase, offsets, cursor);
    scatter_kernel<<<edgeBlocks, 256, 0, stream>>>(ei, cursor, csr);

    // ---- layer 1 ----
    linear2_kernel<<<rowBlocks, 256, 0, stream>>>(X, Wn1, u1, A, out);
    agg_kernel<<<aggBlocks, 256, 0, stream>>>(offsets, csr, out, A, A);

    // ---- layer 2 ----
    linear2_kernel<<<rowBlocks, 256, 0, stream>>>(A, Wn2, u2, out, A);
    agg_kernel<<<aggBlocks, 256, 0, stream>>>(offsets, csr, A, out, out);
}

// Round 6
// 153.908 us; speedup vs baseline: 1.2616x; 1.2616x over previous
//
#include <hip/hip_runtime.h>
#include <hip/hip_fp16.h>
#include <cstdint>
#include <cstddef>
#include <math.h>

// Problem constants (from reference)
#define NNODES 20000
#define NEDGES 320000
#define TDIM   8
#define CDIM   32
#define RROWS  (NNODES * TDIM)           // 160000 rows of 32 floats
#define NELEM  (RROWS * CDIM)            // 5,120,000 elements per [N,T,C] tensor
#define ROWBLK (TDIM * CDIM)             // 256 floats per node

static __device__ __forceinline__ float4 fmax4(float4 a, float4 b) {
    return make_float4(fmaxf(a.x, b.x), fmaxf(a.y, b.y),
                       fmaxf(a.z, b.z), fmaxf(a.w, b.w));
}

static __device__ __forceinline__ unsigned pk2(float a, float b) {
    __half2 h = __floats2half2_rn(a, b);
    return *reinterpret_cast<unsigned*>(&h);
}

// load 4 halves (8B) and convert to float4
static __device__ __forceinline__ float4 ld4h(const char* p) {
    uint2 v = *(const uint2*)p;
    __half2 h0 = *reinterpret_cast<__half2*>(&v.x);
    __half2 h1 = *reinterpret_cast<__half2*>(&v.y);
    float2 f0 = __half22float2(h0);
    float2 f1 = __half22float2(h1);
    return make_float4(f0.x, f0.y, f1.x, f1.y);
}

// ---------------------------------------------------------------------------
// Fused linear kernel: h = in @ W (f32); hu16 = half(h @ U).  One row/thread.
// Weights staged in LDS.
// ---------------------------------------------------------------------------
__global__ __launch_bounds__(256) void linear2_kernel(
    const float* __restrict__ in,   // [RROWS, 32]
    const float* __restrict__ W,    // [32, 32]
    const float* __restrict__ U,    // [32, 32]
    float* __restrict__ h,          // [RROWS, 32] f32
    __half* __restrict__ hu16)      // [RROWS, 32] fp16
{
    __shared__ float sW[CDIM][CDIM];
    __shared__ float sU[CDIM][CDIM];
    int tid = threadIdx.x;
#pragma unroll
    for (int i = 0; i < 4; ++i) {
        int idx = tid + i * 256;
        ((float*)sW)[idx] = W[idx];
        ((float*)sU)[idx] = U[idx];
    }
    __syncthreads();

    int row = blockIdx.x * 256 + tid;
    if (row >= RROWS) return;

    const float* xr = in + (size_t)row * CDIM;
    float x[CDIM];
#pragma unroll
    for (int k = 0; k < CDIM / 4; ++k) {
        float4 v = ((const float4*)xr)[k];
        x[4 * k + 0] = v.x; x[4 * k + 1] = v.y;
        x[4 * k + 2] = v.z; x[4 * k + 3] = v.w;
    }

    float hr[CDIM];
#pragma unroll
    for (int c = 0; c < CDIM; ++c) {
        float acc = 0.f;
#pragma unroll
        for (int k = 0; k < CDIM; ++k) acc += x[k] * sW[k][c];
        hr[c] = acc;
    }

    float* hrow = h + (size_t)row * CDIM;
#pragma unroll
    for (int k = 0; k < CDIM / 4; ++k) {
        ((float4*)hrow)[k] = make_float4(hr[4 * k], hr[4 * k + 1],
                                         hr[4 * k + 2], hr[4 * k + 3]);
    }

#pragma unroll
    for (int c = 0; c < CDIM; ++c) {
        float acc = 0.f;
#pragma unroll
        for (int k = 0; k < CDIM; ++k) acc += hr[k] * sU[k][c];
        x[c] = acc;
    }

    // pack 32 halves (64B) as 4 x uint4
    uint4* dst = (uint4*)((char*)hu16 + (size_t)row * 64);
#pragma unroll
    for (int q = 0; q < 4; ++q) {
        dst[q] = make_uint4(pk2(x[8 * q + 0], x[8 * q + 1]),
                            pk2(x[8 * q + 2], x[8 * q + 3]),
                            pk2(x[8 * q + 4], x[8 * q + 5]),
                            pk2(x[8 * q + 6], x[8 * q + 7]));
    }
}

// ---------------------------------------------------------------------------
// CSR build: hist -> 3-stage parallel scan -> scatter.  Once per launch.
// ---------------------------------------------------------------------------
__global__ __launch_bounds__(256) void zero_counts_kernel(int* __restrict__ counts)
{
    int i = blockIdx.x * 256 + threadIdx.x;
    if (i < NNODES) counts[i] = 0;
}

__global__ __launch_bounds__(256) void hist_kernel(
    const int* __restrict__ ei, int* __restrict__ counts)
{
    int e = blockIdx.x * 256 + threadIdx.x;
    if (e < NEDGES) atomicAdd(&counts[ei[NEDGES + e]], 1);
}

__global__ __launch_bounds__(256) void blocksum_kernel(
    const int* __restrict__ counts, int* __restrict__ bsum)
{
    __shared__ int sd[256];
    int tid = threadIdx.x;
    int i = blockIdx.x * 256 + tid;
    sd[tid] = (i < NNODES) ? counts[i] : 0;
    __syncthreads();
#pragma unroll
    for (int off = 128; off > 0; off >>= 1) {
        if (tid < off) sd[tid] += sd[tid + off];
        __syncthreads();
    }
    if (tid == 0) bsum[blockIdx.x] = sd[0];
}

__global__ __launch_bounds__(128) void bscan_kernel(
    const int* __restrict__ bsum, int* __restrict__ bbase, int nblocks)
{
    __shared__ int sd[128];
    int tid = threadIdx.x;
    int v = (tid < nblocks) ? bsum[tid] : 0;
    sd[tid] = v;
    __syncthreads();
#pragma unroll
    for (int off = 1; off < 128; off <<= 1) {
        int t = (tid >= off) ? sd[tid - off] : 0;
        __syncthreads();
        sd[tid] += t;
        __syncthreads();
    }
    if (tid < nblocks) bbase[tid] = sd[tid] - v;   // exclusive
}

__global__ __launch_bounds__(256) void localscan_kernel(
    const int* __restrict__ counts, const int* __restrict__ bbase,
    int* __restrict__ offsets, int* __restrict__ cursor)
{
    __shared__ int sd[256];
    int tid = threadIdx.x;
    int i = blockIdx.x * 256 + tid;
    int v = (i < NNODES) ? counts[i] : 0;
    sd[tid] = v;
    __syncthreads();
#pragma unroll
    for (int off = 1; off < 256; off <<= 1) {
        int t = (tid >= off) ? sd[tid - off] : 0;
        __syncthreads();
        sd[tid] += t;
        __syncthreads();
    }
    int excl = bbase[blockIdx.x] + sd[tid] - v;
    if (i < NNODES) { offsets[i] = excl; cursor[i] = excl; }
    if (i == NNODES - 1) offsets[NNODES] = NEDGES;
}

__global__ __launch_bounds__(256) void scatter_kernel(
    const int* __restrict__ ei,
    int* __restrict__ cursor,
    int* __restrict__ csr_src)
{
    int e = blockIdx.x * 256 + threadIdx.x;
    if (e < NEDGES) {
        int t = ei[NEDGES + e];
        int pos = atomicAdd(&cursor[t], 1);
        csr_src[pos] = ei[e];
    }
}

// ---------------------------------------------------------------------------
// Aggregation: one wave per node (block = 4 nodes x 1 wave).
// Gather source is fp16 (512B/row, 8B/lane).  Edge loop unrolled by 4 with
// NEXT-iteration csr indices prefetched while current row loads are in
// flight (breaks idx->row serial chain).  Dot = 4 FMA + 3-step shfl in the
// 8-lane tau group.  32-bit addressing.  No LDS/barriers.
// Writes out = leaky_relu(h + agg, 0.01).  `h`/`out` may alias per-thread.
// ---------------------------------------------------------------------------
__global__ __launch_bounds__(256) void agg_kernel(
    const int* __restrict__ offsets,
    const int* __restrict__ csr_src,
    const __half* __restrict__ hu16, // gather source [RROWS,32] fp16
    const float* h,                  // [RROWS,32]
    float* out)                      // [RROWS,32]
{
    int tid = threadIdx.x;
    int n = blockIdx.x * 4 + (tid >> 6);     // node for this wave
    int l64 = tid & 63;                      // tau*8 + li
    uint32_t rowOff = (uint32_t)l64 * 8u;    // byte offset inside 512B row
    const char* hub = (const char*)hu16;

    float4 bv = ld4h(hub + ((uint32_t)n << 9) + rowOff);   // x_i quad

    int k0 = offsets[n];
    int k1 = offsets[n + 1];

    float4 m = make_float4(-INFINITY, -INFINITY, -INFINITY, -INFINITY);

    int k = k0;
    int kend4 = k0 + ((k1 - k0) & ~3);
    int s0, s1, s2, s3;
    if (k < kend4) {
        s0 = csr_src[k + 0]; s1 = csr_src[k + 1];
        s2 = csr_src[k + 2]; s3 = csr_src[k + 3];
    }
    while (k < kend4) {
        // issue current 4 row loads
        const char* p0 = hub + (((uint32_t)s0 << 9) + rowOff);
        const char* p1 = hub + (((uint32_t)s1 << 9) + rowOff);
        const char* p2 = hub + (((uint32_t)s2 << 9) + rowOff);
        const char* p3 = hub + (((uint32_t)s3 << 9) + rowOff);
        uint2 r0 = *(const uint2*)p0;
        uint2 r1 = *(const uint2*)p1;
        uint2 r2 = *(const uint2*)p2;
        uint2 r3 = *(const uint2*)p3;
        k += 4;
        if (k < kend4) {               // prefetch next indices under row latency
            s0 = csr_src[k + 0]; s1 = csr_src[k + 1];
            s2 = csr_src[k + 2]; s3 = csr_src[k + 3];
        }
        float4 a0 = ld4h((const char*)&r0);  // converts in-register
        float4 a1 = ld4h((const char*)&r1);
        float4 a2 = ld4h((const char*)&r2);
        float4 a3 = ld4h((const char*)&r3);
        float q0 = a0.x * bv.x + a0.y * bv.y + a0.z * bv.z + a0.w * bv.w;
        float q1 = a1.x * bv.x + a1.y * bv.y + a1.z * bv.z + a1.w * bv.w;
        float q2 = a2.x * bv.x + a2.y * bv.y + a2.z * bv.z + a2.w * bv.w;
        float q3 = a3.x * bv.x + a3.y * bv.y + a3.z * bv.z + a3.w * bv.w;
        q0 += __shfl_xor(q0, 1); q1 += __shfl_xor(q1, 1);
        q2 += __shfl_xor(q2, 1); q3 += __shfl_xor(q3, 1);
        q0 += __shfl_xor(q0, 2); q1 += __shfl_xor(q1, 2);
        q2 += __shfl_xor(q2, 2); q3 += __shfl_xor(q3, 2);
        q0 += __shfl_xor(q0, 4); q1 += __shfl_xor(q1, 4);
        q2 += __shfl_xor(q2, 4); q3 += __shfl_xor(q3, 4);
        float g0 = 1.f / (1.f + __expf(-q0));
        float g1 = 1.f / (1.f + __expf(-q1));
        float g2 = 1.f / (1.f + __expf(-q2));
        float g3 = 1.f / (1.f + __expf(-q3));
        m = fmax4(m, make_float4(a0.x * g0, a0.y * g0, a0.z * g0, a0.w * g0));
        m = fmax4(m, make_float4(a1.x * g1, a1.y * g1, a1.z * g1, a1.w * g1));
        m = fmax4(m, make_float4(a2.x * g2, a2.y * g2, a2.z * g2, a2.w * g2));
        m = fmax4(m, make_float4(a3.x * g3, a3.y * g3, a3.z * g3, a3.w * g3));
    }
    for (; k < k1; ++k) {
        int s = csr_src[k];
        float4 a0 = ld4h(hub + (((uint32_t)s << 9) + rowOff));
        float q0 = a0.x * bv.x + a0.y * bv.y + a0.z * bv.z + a0.w * bv.w;
        q0 += __shfl_xor(q0, 1);
        q0 += __shfl_xor(q0, 2);
        q0 += __shfl_xor(q0, 4);
        float g0 = 1.f / (1.f + __expf(-q0));
        m = fmax4(m, make_float4(a0.x * g0, a0.y * g0, a0.z * g0, a0.w * g0));
    }

    bool has = (k1 > k0);
    uint32_t nodeOff = (uint32_t)n * 1024u + (uint32_t)l64 * 16u;  // f32 row
    float4 hv = *(const float4*)((const char*)h + nodeOff);
    float ax = has ? m.x : 0.f;
    float ay = has ? m.y : 0.f;
    float az = has ? m.z : 0.f;
    float aw = has ? m.w : 0.f;
    float vx = hv.x + ax, vy = hv.y + ay, vz = hv.z + az, vw = hv.w + aw;
    float4 o;
    o.x = (vx >= 0.f) ? vx : 0.01f * vx;
    o.y = (vy >= 0.f) ? vy : 0.01f * vy;
    o.z = (vz >= 0.f) ? vz : 0.01f * vz;
    o.w = (vw >= 0.f) ? vw : 0.01f * vw;
    *(float4*)((char*)out + nodeOff) = o;
}

// ---------------------------------------------------------------------------
// Orchestration.
// ws: [counts N][offsets N+1][cursor N][bsum 128][bbase 128][csr E][pad]
//     [A: NELEM f32][H16: NELEM half]   (~32 MB total)
// Layer 1: linear2(X)->h1=A, hu16->H16;  agg(H16, h=A)->c1=A (in place)
// Layer 2: linear2(A)->h2=d_out, hu16->H16; agg(H16, h=d_out)->d_out
// ---------------------------------------------------------------------------
extern "C" void kernel_launch(void* const* d_in, const int* in_sizes, int n_in,
                              void* d_out, int out_size, void* d_ws, size_t ws_size,
                              hipStream_t stream)
{
    const float* X   = (const float*)d_in[0];
    const int*   ei  = (const int*)  d_in[1];
    // d_in[2]=edge_attr, d_in[4]=We1, d_in[7]=We2: dead code in reference
    const float* Wn1 = (const float*)d_in[3];
    const float* u1  = (const float*)d_in[5];
    const float* Wn2 = (const float*)d_in[6];
    const float* u2  = (const float*)d_in[8];

    float* out = (float*)d_out;

    int* counts  = (int*)d_ws;
    int* offsets = counts + NNODES;          // NNODES+1
    int* cursor  = offsets + NNODES + 1;
    int* bsum    = cursor + NNODES;          // 128
    int* bbase   = bsum + 128;               // 128
    int* csr     = bbase + 128;              // NEDGES
    float*  A   = (float*)(((uintptr_t)(csr + NEDGES) + 255) & ~(uintptr_t)255);
    __half* H16 = (__half*)(A + NELEM);

    const int rowBlocks  = (RROWS + 255) / 256;    // 625
    const int edgeBlocks = (NEDGES + 255) / 256;   // 1250
    const int nodeBlocks = (NNODES + 255) / 256;   // 79
    const int aggBlocks  = NNODES / 4;             // 5000

    // ---- CSR build (shared by both layers) ----
    zero_counts_kernel<<<nodeBlocks, 256, 0, stream>>>(counts);
    hist_kernel<<<edgeBlocks, 256, 0, stream>>>(ei, counts);
    blocksum_kernel<<<nodeBlocks, 256, 0, stream>>>(counts, bsum);
    bscan_kernel<<<1, 128, 0, stream>>>(bsum, bbase, nodeBlocks);
    localscan_kernel<<<nodeBlocks, 256, 0, stream>>>(counts, bbase, offsets, cursor);
    scatter_kernel<<<edgeBlocks, 256, 0, stream>>>(ei, cursor, csr);

    // ---- layer 1 ----
    linear2_kernel<<<rowBlocks, 256, 0, stream>>>(X, Wn1, u1, A, H16);
    agg_kernel<<<aggBlocks, 256, 0, stream>>>(offsets, csr, H16, A, A);

    // ---- layer 2 ----
    linear2_kernel<<<rowBlocks, 256, 0, stream>>>(A, Wn2, u2, out, H16);
    agg_kernel<<<aggBlocks, 256, 0, stream>>>(offsets, csr, H16, out, out);
}